// Round 2
// baseline (210.070 us; speedup 1.0000x reference)
//
#include <hip/hip_runtime.h>

// Problem constants (reference: T=4096, N_ENVS=2048, fp32)
#define TT    4096
#define NENV  2048
#define N4    (NENV / 4)          // 512 float4 columns
#define L     8                   // timesteps per chunk
#define NCH   (TT / L)            // 512 chunks
#define NBLK  (NCH * 2)           // 1024 blocks (2 blocks x 256 thr per chunk)

#define GAMMA 0.99f
#define GL    (0.99f * 0.95f)

// B = di + c*B ; A = c*A   (descending-i chunk affine, same fp order as R0)
#define STEP_AB(r_, v_, nv_, dn_, A_, B_)                    \
    {                                                        \
        const float nd = (dn_) ? 0.0f : 1.0f;                \
        const float di = (r_) + GAMMA * (nv_) * nd - (v_);   \
        const float c  = GL * nd;                            \
        (B_) = di + c * (B_);                                \
        (A_) = c * (A_);                                     \
    }

// g = di + c*g ; adv = g ; ret = g + v
#define STEP_OUT(r_, v_, nv_, dn_, g_, adv_, ret_)           \
    {                                                        \
        const float nd = (dn_) ? 0.0f : 1.0f;                \
        const float di = (r_) + GAMMA * (nv_) * nd - (v_);   \
        (g_) = di + GL * nd * (g_);                          \
        (adv_) = (g_);                                       \
        (ret_) = (g_) + (v_);                                \
    }

// ---- k2 helpers: 16-chunk groups, descending chunk index ----
#define P2_PREFETCH(abuf, bbuf, grp_)                        \
    _Pragma("unroll")                                        \
    for (int j = 0; j < 16; ++j) {                           \
        const int c = NCH - 1 - (grp_) * 16 - j;             \
        abuf[j] = As[c * NENV + col];                        \
        bbuf[j] = Bs[c * NENV + col];                        \
    }

#define P2_PROCESS(abuf, bbuf, grp_)                         \
    _Pragma("unroll")                                        \
    for (int j = 0; j < 16; ++j) {                           \
        const int c = NCH - 1 - (grp_) * 16 - j;             \
        Bs[c * NENV + col] = g;   /* g entering chunk c */   \
        g = fmaf(abuf[j], g, bbuf[j]);                       \
    }

// ---- k1: per-chunk affine (A,B). All 32 float4 loads hoisted into
//      register arrays BEFORE compute -> deep MLP under the 128-VGPR cap.
__global__ __launch_bounds__(256, 4) void gae_k1(
    const float4* __restrict__ rp,  const float4* __restrict__ vp,
    const float4* __restrict__ np,  const int4*   __restrict__ dp,
    float4* __restrict__ wsA, float4* __restrict__ wsB)
{
    const int chunk = (int)blockIdx.x >> 1;
    const int c4    = (((int)blockIdx.x & 1) << 8) | (int)threadIdx.x;
    const int base  = chunk * (L * N4) + c4;

    float4 R[L], V[L], NV[L]; int4 DN[L];
#pragma unroll
    for (int i = 0; i < L; ++i) R[i]  = rp[base + i * N4];
#pragma unroll
    for (int i = 0; i < L; ++i) NV[i] = np[base + i * N4];
#pragma unroll
    for (int i = 0; i < L; ++i) V[i]  = vp[base + i * N4];
#pragma unroll
    for (int i = 0; i < L; ++i) DN[i] = dp[base + i * N4];

    float Ax = 1.f, Ay = 1.f, Az = 1.f, Aw = 1.f;
    float Bx = 0.f, By = 0.f, Bz = 0.f, Bw = 0.f;
#pragma unroll
    for (int i = L - 1; i >= 0; --i) {
        STEP_AB(R[i].x, V[i].x, NV[i].x, DN[i].x, Ax, Bx);
        STEP_AB(R[i].y, V[i].y, NV[i].y, DN[i].y, Ay, By);
        STEP_AB(R[i].z, V[i].z, NV[i].z, DN[i].z, Az, Bz);
        STEP_AB(R[i].w, V[i].w, NV[i].w, DN[i].w, Aw, Bw);
    }
    wsA[chunk * N4 + c4] = make_float4(Ax, Ay, Az, Aw);
    wsB[chunk * N4 + c4] = make_float4(Bx, By, Bz, Bw);
}

// ---- k2: full-depth serial scan over 512 chunk affines, one thread per
//      scalar column. Overwrites wsB[c] IN PLACE with g entering chunk c
//      (each slot read via prefetch before the same thread overwrites it).
//      512 dependent fmaf ~= 1 us; loads hidden by 2x16-deep prefetch.
__global__ __launch_bounds__(64) void gae_k2(
    const float* __restrict__ As, float* __restrict__ Bs)
{
    const int col = (int)blockIdx.x * 64 + (int)threadIdx.x;   // 32 blocks
    float a0[16], b0[16], a1[16], b1[16];
    float g = 0.0f;
    P2_PREFETCH(a0, b0, 0)
    for (int grp = 0; grp < NCH / 16; grp += 2) {
        P2_PREFETCH(a1, b1, grp + 1)
        P2_PROCESS(a0, b0, grp)
        if (grp + 2 < NCH / 16) { P2_PREFETCH(a0, b0, grp + 2) }
        P2_PROCESS(a1, b1, grp + 1)
    }
}

// ---- k3: read g entering chunk directly (wsB), replay, write outputs.
//      Same hoisted-preload structure as k1; inputs are L3-hot here.
__global__ __launch_bounds__(256, 4) void gae_k3(
    const float4* __restrict__ rp,  const float4* __restrict__ vp,
    const float4* __restrict__ np,  const int4*   __restrict__ dp,
    const float4* __restrict__ gin,
    float4* __restrict__ adv4, float4* __restrict__ ret4)
{
    const int chunk = (int)blockIdx.x >> 1;
    const int c4    = (((int)blockIdx.x & 1) << 8) | (int)threadIdx.x;
    const int base  = chunk * (L * N4) + c4;

    const float4 g0 = gin[chunk * N4 + c4];

    float4 R[L], V[L], NV[L]; int4 DN[L];
#pragma unroll
    for (int i = 0; i < L; ++i) R[i]  = rp[base + i * N4];
#pragma unroll
    for (int i = 0; i < L; ++i) NV[i] = np[base + i * N4];
#pragma unroll
    for (int i = 0; i < L; ++i) V[i]  = vp[base + i * N4];
#pragma unroll
    for (int i = 0; i < L; ++i) DN[i] = dp[base + i * N4];

    float gx = g0.x, gy = g0.y, gz = g0.z, gw = g0.w;
#pragma unroll
    for (int i = L - 1; i >= 0; --i) {
        float4 a, t;
        STEP_OUT(R[i].x, V[i].x, NV[i].x, DN[i].x, gx, a.x, t.x);
        STEP_OUT(R[i].y, V[i].y, NV[i].y, DN[i].y, gy, a.y, t.y);
        STEP_OUT(R[i].z, V[i].z, NV[i].z, DN[i].z, gz, a.z, t.z);
        STEP_OUT(R[i].w, V[i].w, NV[i].w, DN[i].w, gw, a.w, t.w);
        adv4[base + i * N4] = a;
        ret4[base + i * N4] = t;
    }
}

extern "C" void kernel_launch(void* const* d_in, const int* in_sizes, int n_in,
                              void* d_out, int out_size, void* d_ws, size_t ws_size,
                              hipStream_t stream) {
    const float4* rp = (const float4*)d_in[0];
    const float4* vp = (const float4*)d_in[1];
    const float4* np = (const float4*)d_in[2];
    const int4*   dp = (const int4*)d_in[3];

    float4* adv4 = (float4*)d_out;
    float4* ret4 = adv4 + (size_t)TT * N4;

    float4* wsA = (float4*)d_ws;                 // 4 MiB (chunk A)
    float4* wsB = wsA + (size_t)NCH * N4;        // 4 MiB (chunk B -> incoming g)

    gae_k1<<<NBLK, 256, 0, stream>>>(rp, vp, np, dp, wsA, wsB);
    gae_k2<<<NENV / 64, 64, 0, stream>>>((const float*)wsA, (float*)wsB);
    gae_k3<<<NBLK, 256, 0, stream>>>(rp, vp, np, dp, wsB, adv4, ret4);
}